// Round 10
// baseline (108.238 us; speedup 1.0000x reference)
//
#include <hip/hip_runtime.h>
#include <hip/hip_cooperative_groups.h>

namespace cg = cooperative_groups;

// Problem constants (match reference)
constexpr int V     = 50265;   // vocab size
constexpr int PADT  = 1;       // PAD token id
constexpr int BATCH = 512;
constexpr int SEQ   = 512;
constexpr int SS    = 6284;    // vocab section (8 sections cover V)
constexpr int HW4   = 3144;    // 3142 packed u16-pair words, padded to uint4
constexpr int GRID  = BATCH * 4;  // 2048 = 8 blocks/CU * 256 CUs, co-resident

// ONE cooperative kernel (saves k_partial + a dispatch boundary ~5 us).
// Block = (row, quarter). All sync-independent work (ids load, dl reduce,
// partials plain-store, hist zero, token scatter) runs BEFORE grid.sync();
// after the sync each block sums the 512 row-lengths itself (2 KB, L2-hot)
// and then does nothing but stream stores -- no polling concurrent with the
// write stream (R8 lesson: agent-scope spin during streaming = -5x).
// No atomics, no init: partials[b] plain-stored every call -> deterministic.
__global__ __launch_bounds__(256, 8) void k_fused(const int* __restrict__ ids,
                                                  int* __restrict__ partials,
                                                  float* __restrict__ out) {
    __shared__ unsigned hist[HW4];
    __shared__ int s_red[4];
    __shared__ int s_dl;
    __shared__ float s_add;

    const int bs = blockIdx.x;
    const int b = bs >> 2, h = bs & 3;   // row, quarter
    const int t = threadIdx.x;

    const int id0 = ids[b * SEQ + t];
    const int id1 = ids[b * SEQ + 256 + t];

    // row non-PAD length (block reduce over 4 waves)
    int np = ((id0 != PADT) ? 1 : 0) + ((id1 != PADT) ? 1 : 0);
    #pragma unroll
    for (int off = 32; off > 0; off >>= 1) np += __shfl_down(np, off, 64);
    if ((t & 63) == 0) s_red[t >> 6] = np;
    __syncthreads();
    if (t == 0) {
        const int dl = s_red[0] + s_red[1] + s_red[2] + s_red[3];
        s_dl = dl;
        if (h == 0) partials[b] = dl;    // plain store; one writer per row
    }

    // pre-sync: zero hist + scatter section q0 = 2h (LDS-local, no dependency)
    {
        uint4* h4 = (uint4*)hist;
        const uint4 z4 = make_uint4(0u, 0u, 0u, 0u);
        #pragma unroll
        for (int w = t; w < HW4 / 4; w += 256) h4[w] = z4;
        __syncthreads();
        const int v0 = (2 * h) * SS;
        const int vend = (v0 + SS < V) ? (v0 + SS) : V;
        if (id0 != PADT && id0 >= v0 && id0 < vend) {
            const int li = id0 - v0;
            atomicAdd(&hist[li >> 1], 1u << ((li & 1) * 16));
        }
        if (id1 != PADT && id1 >= v0 && id1 < vend) {
            const int li = id1 - v0;
            atomicAdd(&hist[li >> 1], 1u << ((li & 1) * 16));
        }
    }

    cg::this_grid().sync();   // all partials visible; one barrier, then stream

    // total = sum of 512 row lengths (256 thr x 2 loads, L2-broadcast)
    int pv = partials[2 * t] + partials[2 * t + 1];
    #pragma unroll
    for (int off = 32; off > 0; off >>= 1) pv += __shfl_down(pv, off, 64);
    if ((t & 63) == 0) s_red[t >> 6] = pv;
    __syncthreads();
    if (t == 0) {
        const int total = s_red[0] + s_red[1] + s_red[2] + s_red[3];
        // d_avg = dl / (total/BATCH); dl*BATCH <= 2^18, exact in fp32
        const float d_avg = (float)s_dl * (float)BATCH / (float)total;
        s_add = 1.6f * (0.25f + 0.75f * d_avg);  // k*(1-b+b*d_avg)
    }
    __syncthreads();

    const float addend = s_add;
    const int sh = (t & 1) * 16;          // loop-invariant unpack shift
    float* __restrict__ orow = out + (size_t)b * V;

    // stream section q0 (hist already built pre-sync)
    {
        const int v0 = (2 * h) * SS;
        const int vend = (v0 + SS < V) ? (v0 + SS) : V;
        for (int v = v0 + t; v < vend; v += 256) {
            const unsigned cw = hist[(v - v0) >> 1];
            const float fc = (float)((cw >> sh) & 0xffffu);
            orow[v] = (fc * 2.6f) * __builtin_amdgcn_rcpf(fc + addend);
        }
    }
    __syncthreads();

    // section q1 = 2h+1: zero, scatter, stream
    {
        uint4* h4 = (uint4*)hist;
        const uint4 z4 = make_uint4(0u, 0u, 0u, 0u);
        #pragma unroll
        for (int w = t; w < HW4 / 4; w += 256) h4[w] = z4;
        __syncthreads();
        const int v0 = (2 * h + 1) * SS;
        const int vend = (v0 + SS < V) ? (v0 + SS) : V;
        if (id0 != PADT && id0 >= v0 && id0 < vend) {
            const int li = id0 - v0;
            atomicAdd(&hist[li >> 1], 1u << ((li & 1) * 16));
        }
        if (id1 != PADT && id1 >= v0 && id1 < vend) {
            const int li = id1 - v0;
            atomicAdd(&hist[li >> 1], 1u << ((li & 1) * 16));
        }
        __syncthreads();
        for (int v = v0 + t; v < vend; v += 256) {
            const unsigned cw = hist[(v - v0) >> 1];
            const float fc = (float)((cw >> sh) & 0xffffu);
            orow[v] = (fc * 2.6f) * __builtin_amdgcn_rcpf(fc + addend);
        }
    }
}

extern "C" void kernel_launch(void* const* d_in, const int* in_sizes, int n_in,
                              void* d_out, int out_size, void* d_ws, size_t ws_size,
                              hipStream_t stream) {
    const int* ids = (const int*)d_in[0];   // input_ids, int32 [512*512]
    // d_in[1] = beta (unused by the reference computation)
    float* out = (float*)d_out;             // [512 * 50265] fp32
    int* partials = (int*)d_ws;             // BATCH ints of scratch

    void* args[] = {(void*)&ids, (void*)&partials, (void*)&out};
    hipLaunchCooperativeKernel((void*)k_fused, dim3(GRID), dim3(256),
                               args, 0, stream);
}

// Round 11
// 30.047 us; speedup vs baseline: 3.6023x; 3.6023x over previous
//
#include <hip/hip_runtime.h>

// Problem constants (match reference)
constexpr int V     = 50265;   // vocab size
constexpr int PADT  = 1;       // PAD token id
constexpr int BATCH = 512;
constexpr int SEQ   = 512;
constexpr int SS    = 6284;    // vocab section (8 sections cover V; 8*6284>=V)
constexpr int WSL   = SS / 4;  // 1571 elems per wave slice (4 waves/block)
constexpr int HW4   = 3144;    // 3142 packed u16-pair words padded to uint4

// Kernel 1: per-row non-PAD length. All 512 slots written every call
// (d_ws is poisoned; no cross-call state). ~2 us.
__global__ __launch_bounds__(256) void k_rowlen(const int* __restrict__ ids,
                                                int* __restrict__ dl) {
    const int b = blockIdx.x, t = threadIdx.x;
    const int id0 = ids[b * SEQ + t];
    const int id1 = ids[b * SEQ + 256 + t];
    int np = ((id0 != PADT) ? 1 : 0) + ((id1 != PADT) ? 1 : 0);
    #pragma unroll
    for (int off = 32; off > 0; off >>= 1) np += __shfl_down(np, off, 64);
    __shared__ int s[4];
    if ((t & 63) == 0) s[t >> 6] = np;
    __syncthreads();
    if (t == 0) dl[b] = s[0] + s[1] + s[2] + s[3];
}

// Kernel 2: 4096 blocks x 256 thr, one block = (row, section of 6284 cols).
// Phase 1: build 12.6 KB u16-packed LDS hist (cheap: 2 masked atomics/thr).
// Phase 2: DENSE-ZERO the window with compute-free float4 stores -- loop is
//   instruction-identical to the harness fill that demonstrates 6.4 TB/s.
// Phase 3: per-wave s_waitcnt vmcnt(0), then scan own hist stripe and
//   overwrite the few nonzero positions in the wave's OWN just-zeroed 6.1 KB
//   slice -> L2-dirty hits, same-address order guaranteed by the drain.
// No device-scope sync anywhere (R8/R10: that collapses write BW 5x).
__global__ __launch_bounds__(256) void k_fused(const int* __restrict__ ids,
                                               const int* __restrict__ dl,
                                               float* __restrict__ out) {
    __shared__ unsigned hist[HW4];

    const int bs = blockIdx.x;
    const int b = bs >> 3, sec = bs & 7;   // row, section
    const int t = threadIdx.x;
    const int w = t >> 6, lane = t & 63;
    const int v0 = sec * SS;
    const int ve_rel = ((v0 + SS < V) ? SS : (V - v0));  // section length

    // issue all global loads up front; latency hides under hist build + zeros
    const int4* dl4 = (const int4*)dl;
    const int4 da = dl4[2 * lane];         // each wave redundantly covers
    const int4 db = dl4[2 * lane + 1];     // dl[0..511] (8 ints/lane)
    const int mydl = dl[b];                // uniform -> scalar load
    const int id0 = ids[b * SEQ + t];
    const int id1 = ids[b * SEQ + 256 + t];

    // zero hist (786 uint4 words / 256 thr)
    uint4* h4 = (uint4*)hist;
    const uint4 z4 = make_uint4(0u, 0u, 0u, 0u);
    for (int q = t; q < HW4 / 4; q += 256) h4[q] = z4;
    __syncthreads();

    // scatter my 2 tokens if in this section (u16-packed; counts <= 512)
    if (id0 != PADT && id0 >= v0 && id0 < v0 + ve_rel) {
        const int li = id0 - v0;
        atomicAdd(&hist[li >> 1], 1u << ((li & 1) * 16));
    }
    if (id1 != PADT && id1 >= v0 && id1 < v0 + ve_rel) {
        const int li = id1 - v0;
        atomicAdd(&hist[li >> 1], 1u << ((li & 1) * 16));
    }
    __syncthreads();   // hist complete; no more barriers below

    // ---- phase 2: dense zero-stream of this wave's slice (PURE stores) ----
    float* __restrict__ orow = out + (size_t)b * V;
    const int sv = w * WSL;                         // slice start (rel)
    const int ev = ((sv + WSL < ve_rel) ? (sv + WSL) : ve_rel);  // slice end

    {
        const int g0 = b * V + v0 + sv;             // global elem index
        const int a = (4 - (g0 & 3)) & 3;           // elems to 16B alignment
        // head (<=3 scalar)
        if (lane < a && sv + lane < ev) orow[v0 + sv + lane] = 0.0f;
        // aligned float4 body -- compute-free, fill-identical
        const int base = sv + a;
        const int n4 = (ev - base) >> 2;
        float4* __restrict__ o4 = (float4*)(orow + v0 + base);
        const float4 zf4 = make_float4(0.f, 0.f, 0.f, 0.f);
        for (int g = lane; g < n4; g += 64) o4[g] = zf4;
        // tail (<=3 scalar)
        const int tv = base + (n4 << 2);
        if (lane < ev - tv) orow[v0 + tv + lane] = 0.0f;
    }

    // wave-local drain: own zero-stores committed to L2 (and dl loads done)
    asm volatile("s_waitcnt vmcnt(0)" ::: "memory");

    // ---- total + addend (redundant per wave; shfl only, no barriers) ----
    int pv = da.x + da.y + da.z + da.w + db.x + db.y + db.z + db.w;
    #pragma unroll
    for (int off = 32; off > 0; off >>= 1) pv += __shfl_down(pv, off, 64);
    const int total = __shfl(pv, 0, 64);
    // d_avg = dl / (total/BATCH); dl*BATCH <= 2^18, exact in fp32
    const float d_avg = (float)mydl * (float)BATCH / (float)total;
    const float addend = 1.6f * (0.25f + 0.75f * d_avg);  // k*(1-b+b*d_avg)

    // ---- phase 3: scan own hist stripe, overwrite nonzeros in own slice ----
    const int wlo = sv >> 1;
    const int whi = (ev + 1) >> 1;
    for (int wi = wlo + lane; wi < whi; wi += 64) {
        const unsigned cw = hist[wi];
        if (cw) {
            const int vr0 = 2 * wi;
            const unsigned clo = cw & 0xffffu;
            const unsigned chi = cw >> 16;
            if (clo && vr0 >= sv && vr0 < ev) {
                const float fc = (float)clo;
                orow[v0 + vr0] = (fc * 2.6f) * __builtin_amdgcn_rcpf(fc + addend);
            }
            if (chi && vr0 + 1 >= sv && vr0 + 1 < ev) {
                const float fc = (float)chi;
                orow[v0 + vr0 + 1] = (fc * 2.6f) * __builtin_amdgcn_rcpf(fc + addend);
            }
        }
    }
}

extern "C" void kernel_launch(void* const* d_in, const int* in_sizes, int n_in,
                              void* d_out, int out_size, void* d_ws, size_t ws_size,
                              hipStream_t stream) {
    const int* ids = (const int*)d_in[0];   // input_ids, int32 [512*512]
    // d_in[1] = beta (unused by the reference computation)
    float* out = (float*)d_out;             // [512 * 50265] fp32
    int* dl = (int*)d_ws;                   // 512 ints: per-row lengths

    k_rowlen<<<BATCH, 256, 0, stream>>>(ids, dl);
    k_fused<<<BATCH * 8, 256, 0, stream>>>(ids, dl, out);
}